// Round 17
// baseline (432.779 us; speedup 1.0000x reference)
//
#include <hip/hip_runtime.h>

#define K_DIM   4096
#define N_DIM   4096
#define M_ROWS  8192
#define KF      (K_DIM / 4)      // 1024 float4 per x/A row
#define NF      (N_DIM / 4)      // 1024 float4 per out/Bt row

typedef __attribute__((ext_vector_type(8))) short short8v;   // 8 bf16
typedef __attribute__((ext_vector_type(4))) float f32x4;

// round-to-nearest-even fp32 -> bf16 bits
static __device__ __forceinline__ short f2bf(float f) {
    const unsigned u = __builtin_bit_cast(unsigned, f);
    return (short)((u + 0x7FFFu + ((u >> 16) & 1u)) >> 16);
}

// ---------------------------------------------------------------------------
// Prep: transpose B [4096][16] -> Bt [16][4096]  (256 KB, ~2 us)
__global__ __launch_bounds__(256) void lora_prep(const float* __restrict__ B,
                                                 float* __restrict__ Bt) {
    const int i4 = blockIdx.x * 256 + threadIdx.x;   // 0..16383
    const int r  = i4 >> 10;             // Bt row 0..15
    const int c0 = (i4 & 1023) * 4;      // first of 4 cols
    float4 v;
    v.x = B[(size_t)(c0 + 0) * 16 + r];
    v.y = B[(size_t)(c0 + 1) * 16 + r];
    v.z = B[(size_t)(c0 + 2) * 16 + r];
    v.w = B[(size_t)(c0 + 3) * 16 + r];
    ((float4*)Bt)[i4] = v;
}

// ---------------------------------------------------------------------------
// Fused LoRA, register-disciplined (round-14 spill fix):
//   __launch_bounds__(256,4) -> hard 128-VGPR cap; unroll 2 keeps <=2
//   iterations of loads in flight. Phase live sets: P1 ~70, P2 ~90 regs.
// Phase 1: wave wv = K-quarter; 32 x mfma_f32_16x16x32_bf16 -> 16x16 t tile.
// Reduce via 4 KB LDS (fixed order). Phase 2: stream 16x4096 out tile,
// bv[16] 1KB coalesced Bt bursts (L2-hot), t broadcast from LDS.
__global__ __launch_bounds__(256, 4) void lora_fused(const float* __restrict__ x,
                                                     const float* __restrict__ A,
                                                     const float* __restrict__ Bt,
                                                     float* __restrict__ out) {
    __shared__ float part[4][256];        // per-wave t partials, 4 KB
    __shared__ float t_s[256];            // reduced t tile: [row][r], 1 KB

    const int tid  = threadIdx.x;
    const int wv   = tid >> 6;            // K quarter
    const int lane = tid & 63;
    const int row0 = blockIdx.x * 16;

    const int mrow = row0 + (lane & 15);  // x row this lane feeds (A-op)
    const int acol = lane & 15;           // A row = t column (B-op)
    const int og   = (lane >> 4) * 2;     // float4 pair within K=32 octet

    const float4* x4 = (const float4*)x;
    const float4* A4 = (const float4*)A;
    const size_t xbase = (size_t)mrow * KF;
    const size_t abase = (size_t)acol * KF;
    const int kq = wv * 256;              // K-quarter base in float4 units

    f32x4 acc = {0.f, 0.f, 0.f, 0.f};

    #pragma unroll 2
    for (int it = 0; it < 32; ++it) {
        const int kf = kq + it * 8 + og;
        const float4 xa = x4[xbase + kf];
        const float4 xb = x4[xbase + kf + 1];
        const float4 aa = A4[abase + kf];
        const float4 ab = A4[abase + kf + 1];

        short8v af, bf;
        af[0] = f2bf(xa.x); af[1] = f2bf(xa.y);
        af[2] = f2bf(xa.z); af[3] = f2bf(xa.w);
        af[4] = f2bf(xb.x); af[5] = f2bf(xb.y);
        af[6] = f2bf(xb.z); af[7] = f2bf(xb.w);
        bf[0] = f2bf(aa.x); bf[1] = f2bf(aa.y);
        bf[2] = f2bf(aa.z); bf[3] = f2bf(aa.w);
        bf[4] = f2bf(ab.x); bf[5] = f2bf(ab.y);
        bf[6] = f2bf(ab.z); bf[7] = f2bf(ab.w);

        acc = __builtin_amdgcn_mfma_f32_16x16x32_bf16(af, bf, acc, 0, 0, 0);
    }

    // C layout: lane l reg v -> local row (l>>4)*4+v, col l&15
    #pragma unroll
    for (int v = 0; v < 4; ++v)
        part[wv][((lane >> 4) * 4 + v) * 16 + (lane & 15)] = acc[v];
    __syncthreads();

    // fixed-order reduction: t_s[idx] = sum over the 4 K-quarters
    t_s[tid] = ((part[0][tid] + part[1][tid]) +
                (part[2][tid] + part[3][tid]));
    __syncthreads();

    // ---- phase 2: out[row0..row0+15][:] = t_s @ Bt ----
    const float4* Bt4 = (const float4*)Bt;
    const float4* ts4 = (const float4*)t_s;
    float4* out4 = (float4*)out;

    for (int ch = 0; ch < 4; ++ch) {
        const int c4 = ch * 256 + tid;    // float4 column index
        float4 bv[16];
        #pragma unroll
        for (int r = 0; r < 16; ++r)
            bv[r] = Bt4[r * NF + c4];     // 1 KB coalesced burst, L2-hot
        #pragma unroll
        for (int row = 0; row < 16; ++row) {
            float4 tq[4];
            #pragma unroll
            for (int q = 0; q < 4; ++q)
                tq[q] = ts4[row * 4 + q]; // LDS broadcast
            float4 o = {0.f, 0.f, 0.f, 0.f};
            #pragma unroll
            for (int r = 0; r < 16; ++r) {
                const float4 tv4 = tq[r >> 2];
                const float tv = ((r & 3) == 0) ? tv4.x :
                                 ((r & 3) == 1) ? tv4.y :
                                 ((r & 3) == 2) ? tv4.z : tv4.w;
                o.x = fmaf(tv, bv[r].x, o.x);
                o.y = fmaf(tv, bv[r].y, o.y);
                o.z = fmaf(tv, bv[r].z, o.z);
                o.w = fmaf(tv, bv[r].w, o.w);
            }
            out4[(size_t)(row0 + row) * NF + c4] = o;
        }
    }
}

extern "C" void kernel_launch(void* const* d_in, const int* in_sizes, int n_in,
                              void* d_out, int out_size, void* d_ws, size_t ws_size,
                              hipStream_t stream) {
    const float* x = (const float*)d_in[0];            // [4,2048,4096]
    const float* B = (const float*)d_in[1];            // [4096,16]
    const float* A = (const float*)d_in[2];            // [16,4096]
    float* out = (float*)d_out;                        // [4,2048,4096]

    float* Bt = (float*)d_ws;                          // [16][4096], 256 KB

    lora_prep<<<64, 256, 0, stream>>>(B, Bt);
    lora_fused<<<M_ROWS / 16, 256, 0, stream>>>(x, A, Bt, out);
}

// Round 18
// 63.652 us; speedup vs baseline: 6.7992x; 6.7992x over previous
//
#include <hip/hip_runtime.h>

#define K_DIM   4096
#define N_DIM   4096
#define M_ROWS  8192
#define KF      (K_DIM / 4)      // 1024 float4 per x/A row
#define NF      (N_DIM / 4)      // 1024 float4 per out/Bt row

typedef __attribute__((ext_vector_type(8))) short short8v;   // 8 bf16
typedef __attribute__((ext_vector_type(4))) float f32x4;

// round-to-nearest-even fp32 -> bf16 bits
static __device__ __forceinline__ short f2bf(float f) {
    const unsigned u = __builtin_bit_cast(unsigned, f);
    return (short)((u + 0x7FFFu + ((u >> 16) & 1u)) >> 16);
}

__device__ __forceinline__ void fma_s4(float4& o, float s, const float4 b) {
    o.x = fmaf(s, b.x, o.x);
    o.y = fmaf(s, b.y, o.y);
    o.z = fmaf(s, b.z, o.z);
    o.w = fmaf(s, b.w, o.w);
}

// ---------------------------------------------------------------------------
// Prep: transpose B [4096][16] -> Bt [16][4096]  (256 KB, ~2 us)
__global__ __launch_bounds__(256) void lora_prep(const float* __restrict__ B,
                                                 float* __restrict__ Bt) {
    const int i4 = blockIdx.x * 256 + threadIdx.x;   // 0..16383
    const int r  = i4 >> 10;             // Bt row 0..15
    const int c0 = (i4 & 1023) * 4;      // first of 4 cols
    float4 v;
    v.x = B[(size_t)(c0 + 0) * 16 + r];
    v.y = B[(size_t)(c0 + 1) * 16 + r];
    v.z = B[(size_t)(c0 + 2) * 16 + r];
    v.w = B[(size_t)(c0 + 3) * 16 + r];
    ((float4*)Bt)[i4] = v;
}

// ---------------------------------------------------------------------------
// Fused LoRA, structurally register-lean phase 2 (round-17 fix):
//   no launch-bounds cap; phase-2 keeps only 8 Bt rows + 8 row-accumulators
//   live at a time (two r-halves, sched_barrier(0) between so the second
//   bv batch cannot be hoisted -> no bv[16] resurrection, no spill).
// Phase 1: wave wv = K-quarter; 32 x mfma_f32_16x16x32_bf16 -> 16x16 t tile.
// Reduce via 4 KB LDS. t never touches HBM; pipelined blocks overlap
// x-reads with out-writes at the HBM controller.
__global__ __launch_bounds__(256) void lora_fused(const float* __restrict__ x,
                                                  const float* __restrict__ A,
                                                  const float* __restrict__ Bt,
                                                  float* __restrict__ out) {
    __shared__ float part[4][256];        // per-wave t partials, 4 KB
    __shared__ float t_s[256];            // reduced t tile: [row][r], 1 KB

    const int tid  = threadIdx.x;
    const int wv   = tid >> 6;            // K quarter
    const int lane = tid & 63;
    const int row0 = blockIdx.x * 16;

    const int mrow = row0 + (lane & 15);  // x row this lane feeds (A-op)
    const int acol = lane & 15;           // A row = t column (B-op)
    const int og   = (lane >> 4) * 2;     // float4 pair within K=32 octet

    const float4* x4 = (const float4*)x;
    const float4* A4 = (const float4*)A;
    const size_t xbase = (size_t)mrow * KF;
    const size_t abase = (size_t)acol * KF;
    const int kq = wv * 256;              // K-quarter base in float4 units

    f32x4 acc = {0.f, 0.f, 0.f, 0.f};

    #pragma unroll 2
    for (int it = 0; it < 32; ++it) {
        const int kf = kq + it * 8 + og;
        const float4 xa = x4[xbase + kf];
        const float4 xb = x4[xbase + kf + 1];
        const float4 aa = A4[abase + kf];
        const float4 ab = A4[abase + kf + 1];

        short8v af, bf;
        af[0] = f2bf(xa.x); af[1] = f2bf(xa.y);
        af[2] = f2bf(xa.z); af[3] = f2bf(xa.w);
        af[4] = f2bf(xb.x); af[5] = f2bf(xb.y);
        af[6] = f2bf(xb.z); af[7] = f2bf(xb.w);
        bf[0] = f2bf(aa.x); bf[1] = f2bf(aa.y);
        bf[2] = f2bf(aa.z); bf[3] = f2bf(aa.w);
        bf[4] = f2bf(ab.x); bf[5] = f2bf(ab.y);
        bf[6] = f2bf(ab.z); bf[7] = f2bf(ab.w);

        acc = __builtin_amdgcn_mfma_f32_16x16x32_bf16(af, bf, acc, 0, 0, 0);
    }

    // C layout: lane l reg v -> local row (l>>4)*4+v, col l&15
    #pragma unroll
    for (int v = 0; v < 4; ++v)
        part[wv][((lane >> 4) * 4 + v) * 16 + (lane & 15)] = acc[v];
    __syncthreads();

    // fixed-order reduction: t_s[idx] = sum over the 4 K-quarters
    t_s[tid] = ((part[0][tid] + part[1][tid]) +
                (part[2][tid] + part[3][tid]));
    __syncthreads();

    // ---- phase 2: out[row0..row0+15][:] = t_s @ Bt, register-lean ----
    const float4* Bt4 = (const float4*)Bt;
    const float4* ts4 = (const float4*)t_s;
    float4* out4 = (float4*)out;

    for (int ch = 0; ch < 4; ++ch) {
        const int c4 = ch * 256 + tid;    // float4 column index
        #pragma unroll
        for (int g = 0; g < 2; ++g) {     // 8-row group
            float4 o[8];
            #pragma unroll
            for (int w = 0; w < 8; ++w) o[w] = {0.f, 0.f, 0.f, 0.f};

            // ---- r half 0: Bt rows 0..7 ----
            {
                float4 bv[8];
                #pragma unroll
                for (int r = 0; r < 8; ++r)
                    bv[r] = Bt4[r * NF + c4];        // 1KB bursts, L2-hot
                #pragma unroll
                for (int w = 0; w < 8; ++w) {
                    const float4 tq0 = ts4[(g * 8 + w) * 4 + 0];
                    const float4 tq1 = ts4[(g * 8 + w) * 4 + 1];
                    fma_s4(o[w], tq0.x, bv[0]);
                    fma_s4(o[w], tq0.y, bv[1]);
                    fma_s4(o[w], tq0.z, bv[2]);
                    fma_s4(o[w], tq0.w, bv[3]);
                    fma_s4(o[w], tq1.x, bv[4]);
                    fma_s4(o[w], tq1.y, bv[5]);
                    fma_s4(o[w], tq1.z, bv[6]);
                    fma_s4(o[w], tq1.w, bv[7]);
                }
            }
            __builtin_amdgcn_sched_barrier(0);       // bv half-1 not hoisted
            // ---- r half 1: Bt rows 8..15 ----
            {
                float4 bv[8];
                #pragma unroll
                for (int r = 0; r < 8; ++r)
                    bv[r] = Bt4[(8 + r) * NF + c4];
                #pragma unroll
                for (int w = 0; w < 8; ++w) {
                    const float4 tq2 = ts4[(g * 8 + w) * 4 + 2];
                    const float4 tq3 = ts4[(g * 8 + w) * 4 + 3];
                    fma_s4(o[w], tq2.x, bv[0]);
                    fma_s4(o[w], tq2.y, bv[1]);
                    fma_s4(o[w], tq2.z, bv[2]);
                    fma_s4(o[w], tq2.w, bv[3]);
                    fma_s4(o[w], tq3.x, bv[4]);
                    fma_s4(o[w], tq3.y, bv[5]);
                    fma_s4(o[w], tq3.z, bv[6]);
                    fma_s4(o[w], tq3.w, bv[7]);
                }
            }
            #pragma unroll
            for (int w = 0; w < 8; ++w)
                out4[(size_t)(row0 + g * 8 + w) * NF + c4] = o[w];
        }
    }
}

extern "C" void kernel_launch(void* const* d_in, const int* in_sizes, int n_in,
                              void* d_out, int out_size, void* d_ws, size_t ws_size,
                              hipStream_t stream) {
    const float* x = (const float*)d_in[0];            // [4,2048,4096]
    const float* B = (const float*)d_in[1];            // [4096,16]
    const float* A = (const float*)d_in[2];            // [16,4096]
    float* out = (float*)d_out;                        // [4,2048,4096]

    float* Bt = (float*)d_ws;                          // [16][4096], 256 KB

    lora_prep<<<64, 256, 0, stream>>>(B, Bt);
    lora_fused<<<M_ROWS / 16, 256, 0, stream>>>(x, A, Bt, out);
}